// Round 8
// baseline (620.155 us; speedup 1.0000x reference)
//
#include <hip/hip_runtime.h>
#include <hip/hip_bf16.h>
#include <stdint.h>

typedef __bf16 bf16x8 __attribute__((ext_vector_type(8)));
typedef float f32x4 __attribute__((ext_vector_type(4)));
typedef unsigned short u16x8 __attribute__((ext_vector_type(8)));

// float -> bf16 round-to-nearest-even (bit trick; inputs are finite here)
__device__ inline unsigned short f2bf_rne(float f) {
  unsigned int u = __float_as_uint(f);
  u += 0x7fffu + ((u >> 16) & 1u);
  return (unsigned short)(u >> 16);
}

// w = mu + eps * exp(0.5*lv), packed bf16. 8 elems/thread, 16B store.
__global__ __launch_bounds__(256) void prep_weight(
    const float4* __restrict__ mu, const float4* __restrict__ lv,
    const float4* __restrict__ eps, u16x8* __restrict__ wbf, int n8) {
  int i = blockIdx.x * 256 + threadIdx.x;
  if (i >= n8) return;
  float4 m0 = mu[2 * i], m1 = mu[2 * i + 1];
  float4 v0 = lv[2 * i], v1 = lv[2 * i + 1];
  float4 e0 = eps[2 * i], e1 = eps[2 * i + 1];
  u16x8 p;
  p[0] = f2bf_rne(m0.x + e0.x * __expf(0.5f * v0.x));
  p[1] = f2bf_rne(m0.y + e0.y * __expf(0.5f * v0.y));
  p[2] = f2bf_rne(m0.z + e0.z * __expf(0.5f * v0.z));
  p[3] = f2bf_rne(m0.w + e0.w * __expf(0.5f * v0.w));
  p[4] = f2bf_rne(m1.x + e1.x * __expf(0.5f * v1.x));
  p[5] = f2bf_rne(m1.y + e1.y * __expf(0.5f * v1.y));
  p[6] = f2bf_rne(m1.z + e1.z * __expf(0.5f * v1.z));
  p[7] = f2bf_rne(m1.w + e1.w * __expf(0.5f * v1.w));
  wbf[i] = p;
}

__global__ __launch_bounds__(256) void prep_x(
    const float4* __restrict__ x, u16x8* __restrict__ xbf, int n8) {
  int i = blockIdx.x * 256 + threadIdx.x;
  if (i >= n8) return;
  float4 m0 = x[2 * i], m1 = x[2 * i + 1];
  u16x8 p;
  p[0] = f2bf_rne(m0.x); p[1] = f2bf_rne(m0.y);
  p[2] = f2bf_rne(m0.z); p[3] = f2bf_rne(m0.w);
  p[4] = f2bf_rne(m1.x); p[5] = f2bf_rne(m1.y);
  p[6] = f2bf_rne(m1.z); p[7] = f2bf_rne(m1.w);
  xbf[i] = p;
}

// C[M,N] = A[M,K]*B[N,K]^T + bias(N). 256x256 tile, BK=64, 512 thr = 8 waves
// (2M x 4N), per-wave 128x64: acc[8][4], 64 MFMA/K-tile in 4 phases of 16.
// R8: m201-faithful phase discipline. Each phase:
//   { ds_reads for THIS phase's quadrant | stage issues } -> s_barrier ->
//   lgkmcnt(0)+sched_barrier (drain AFTER the barrier, per-wave) ->
//   setprio(1) 16 MFMA setprio(0) -> s_barrier.
// Drain-after-barrier is the R5->R8 fix: waves cross barrier1 with reads in
// flight and drain only their OWN 4-12 reads, so first-drained waves MFMA
// while the LDS pipe still serves later waves (cross-wave LDS||MFMA overlap).
// R5 drained before the barrier -> zero overlap -> 4x(LDS 565cy + MFMA 620cy)
// = 5740cy/tile = its measured 38%. Predicted here: ~60%.
// Phases: P0 reads a0(8)+b01(4), Q0 = a0 x b01.
//         P1 reads a1(8),        Q1 = a1 x b01; stage A-low(t+2)  [2 GLL]
//         P2 reads b23(4),       Q2 = a1 x b23; stage A-high(t+2) [2 GLL]
//         P3 no reads,           Q3 = a0 x b23; stage B(t+2) [4 GLL]; vmcnt.
// WAR proofs: A rows 0-63 last read in P0 (a0), published by P0's barrier2 ->
// stage at P1. A rows 64-127 read in P1 (a1) -> stage at P2. B rows: b01 (P0)
// + b23 (P2, published by P2's barrier2) -> stage at P3.
// vmcnt(8) once per tile at P3: outstanding = t+2's 8 (this tile) + t+1's 8
// (previous tile) -> retires exactly t+1; NEVER drains to 0 mid-loop.
// Registers: 24 frags (96 VGPR) + acc (128) — identical to R5/R7; R6 proved
// ANY extra pipeline state spills at 2 waves/SIMD.
// LDS 128KB, 128B rows, verified zero-conflict XOR swizzle (granule g of row
// r holds global granule g^(r&7); read pg=((kk>>3)+gsel)^(mrow&7)).
__global__ __launch_bounds__(512, 2) void gemm_bt_bias(
    const unsigned short* __restrict__ A,   // [M][K] bf16 bits
    const unsigned short* __restrict__ B,   // [N][K] bf16 bits
    const float* __restrict__ bmu, const float* __restrict__ blv,
    const float* __restrict__ beps,
    float* __restrict__ C, int M, int N, int K) {
  __shared__ __align__(16) unsigned short As[2][2][128 * 64];  // 64 KB
  __shared__ __align__(16) unsigned short Bs[2][2][128 * 64];  // 64 KB

  const int tid  = threadIdx.x;
  const int wave = tid >> 6;
  const int lane = tid & 63;
  const int wm = wave >> 2;   // 0..1  (M half)
  const int wn = wave & 3;    // 0..3  (N quarter)

  const int rowA0 = blockIdx.y * 256;
  const int rowB0 = blockIdx.x * 256;

  const int srow = tid >> 3;                       // 0..63
  const int scol = ((tid & 7) ^ (srow & 7)) * 8;
  const unsigned short* pA = A + (size_t)(rowA0 + srow) * K + scol;
  const unsigned short* pB = B + (size_t)(rowB0 + srow) * K + scol;
  const int dep = wave * 512;   // wave-uniform deposit base (elems) per round

#define GLL(srcp, dstp)                                                     \
  __builtin_amdgcn_global_load_lds(                                         \
      (const __attribute__((address_space(1))) unsigned int*)(srcp),        \
      (__attribute__((address_space(3))) unsigned int*)(dstp), 16, 0, 0)

  // single-GLL staging units: rows 0-63 (LO) / 64-127 (HI) of half h
#define SA_LO(kt, b, h) GLL(pA + (size_t)((h) * 128) * K + (size_t)(kt) * 64, \
                            &As[b][h][dep])
#define SA_HI(kt, b, h) GLL(pA + (size_t)((h) * 128 + 64) * K + (size_t)(kt) * 64, \
                            &As[b][h][4096 + dep])
#define SB_LO(kt, b, h) GLL(pB + (size_t)((h) * 128) * K + (size_t)(kt) * 64, \
                            &Bs[b][h][dep])
#define SB_HI(kt, b, h) GLL(pB + (size_t)((h) * 128 + 64) * K + (size_t)(kt) * 64, \
                            &Bs[b][h][4096 + dep])

#define FENCE() __builtin_amdgcn_sched_barrier(0)
#define BAR1()  do { FENCE(); __builtin_amdgcn_s_barrier(); FENCE(); } while (0)
#define DRAIN() do { asm volatile("s_waitcnt lgkmcnt(0)" ::: "memory"); FENCE(); } while (0)
#define BAR2()  do { FENCE(); __builtin_amdgcn_s_barrier(); FENCE(); } while (0)

  f32x4 acc[8][4];
#pragma unroll
  for (int i = 0; i < 8; ++i)
#pragma unroll
    for (int j = 0; j < 4; ++j)
      acc[i][j] = (f32x4){0.f, 0.f, 0.f, 0.f};

  const int mrow = lane & 15;   // fragment row
  const int gsel = lane >> 4;   // k-granule select 0..3
  const int pgL = (gsel ^ (mrow & 7)) * 8;         // kk=0
  const int pgH = ((4 + gsel) ^ (mrow & 7)) * 8;   // kk=32
  const int aoff = mrow * 64;
  const int boff = ((wn & 1) * 64 + mrow) * 64;

  // prologue: stage tiles 0,1; certify tile 0 (tile 1's 8 stay in flight).
  SA_LO(0, 0, 0); SA_LO(0, 0, 1); SA_HI(0, 0, 0); SA_HI(0, 0, 1);
  SB_LO(0, 0, 0); SB_LO(0, 0, 1); SB_HI(0, 0, 0); SB_HI(0, 0, 1);
  SA_LO(1, 1, 0); SA_LO(1, 1, 1); SA_HI(1, 1, 0); SA_HI(1, 1, 1);
  SB_LO(1, 1, 0); SB_LO(1, 1, 1); SB_HI(1, 1, 0); SB_HI(1, 1, 1);
  asm volatile("s_waitcnt vmcnt(8)" ::: "memory");
  __builtin_amdgcn_s_barrier();
  FENCE();

  bf16x8 a0[4][2], a1[4][2], b01[2][2], b23[2][2];

  const int NT = K / 64;   // 64
  for (int t = 0; t < NT; ++t) {
    const int c = t & 1;
    const unsigned short* as_ = &As[c][wm][0];
    const unsigned short* bs_ = &Bs[c][wn >> 1][0];
    const bool pf = (t + 2 < NT);
    const bool pr = (t + 1 < NT);

    // ---- P0: reads a0(8)+b01(4); Q0 = a0 x b01 ----
#pragma unroll
    for (int mi = 0; mi < 4; ++mi) {
      a0[mi][0] = *(const bf16x8*)&as_[aoff + mi * 1024 + pgL];
      a0[mi][1] = *(const bf16x8*)&as_[aoff + mi * 1024 + pgH];
    }
#pragma unroll
    for (int ni = 0; ni < 2; ++ni) {
      b01[ni][0] = *(const bf16x8*)&bs_[boff + ni * 1024 + pgL];
      b01[ni][1] = *(const bf16x8*)&bs_[boff + ni * 1024 + pgH];
    }
    BAR1(); DRAIN();
    __builtin_amdgcn_s_setprio(1);
#pragma unroll
    for (int kk = 0; kk < 2; ++kk)
#pragma unroll
      for (int mi = 0; mi < 4; ++mi)
#pragma unroll
        for (int ni = 0; ni < 2; ++ni)
          acc[mi][ni] = __builtin_amdgcn_mfma_f32_16x16x32_bf16(
              a0[mi][kk], b01[ni][kk], acc[mi][ni], 0, 0, 0);
    __builtin_amdgcn_s_setprio(0);
    BAR2();

    // ---- P1: reads a1(8); stage A-low(t+2); Q1 = a1 x b01 ----
#pragma unroll
    for (int mi = 0; mi < 4; ++mi) {
      a1[mi][0] = *(const bf16x8*)&as_[aoff + (mi + 4) * 1024 + pgL];
      a1[mi][1] = *(const bf16x8*)&as_[aoff + (mi + 4) * 1024 + pgH];
    }
    if (pf) { SA_LO(t + 2, c, 0); SA_LO(t + 2, c, 1); }
    BAR1(); DRAIN();
    __builtin_amdgcn_s_setprio(1);
#pragma unroll
    for (int kk = 0; kk < 2; ++kk)
#pragma unroll
      for (int mi = 0; mi < 4; ++mi)
#pragma unroll
        for (int ni = 0; ni < 2; ++ni)
          acc[mi + 4][ni] = __builtin_amdgcn_mfma_f32_16x16x32_bf16(
              a1[mi][kk], b01[ni][kk], acc[mi + 4][ni], 0, 0, 0);
    __builtin_amdgcn_s_setprio(0);
    BAR2();

    // ---- P2: reads b23(4); stage A-high(t+2); Q2 = a1 x b23 ----
#pragma unroll
    for (int ni = 0; ni < 2; ++ni) {
      b23[ni][0] = *(const bf16x8*)&bs_[boff + (ni + 2) * 1024 + pgL];
      b23[ni][1] = *(const bf16x8*)&bs_[boff + (ni + 2) * 1024 + pgH];
    }
    if (pf) { SA_HI(t + 2, c, 0); SA_HI(t + 2, c, 1); }
    BAR1(); DRAIN();
    __builtin_amdgcn_s_setprio(1);
#pragma unroll
    for (int kk = 0; kk < 2; ++kk)
#pragma unroll
      for (int mi = 0; mi < 4; ++mi)
#pragma unroll
        for (int ni = 0; ni < 2; ++ni)
          acc[mi + 4][ni + 2] = __builtin_amdgcn_mfma_f32_16x16x32_bf16(
              a1[mi][kk], b23[ni][kk], acc[mi + 4][ni + 2], 0, 0, 0);
    __builtin_amdgcn_s_setprio(0);
    BAR2();

    // ---- P3: stage B(t+2); Q3 = a0 x b23 (register-only); counted vmcnt ----
    if (pf) {
      SB_LO(t + 2, c, 0); SB_LO(t + 2, c, 1);
      SB_HI(t + 2, c, 0); SB_HI(t + 2, c, 1);
    }
    BAR1();
    __builtin_amdgcn_s_setprio(1);
#pragma unroll
    for (int kk = 0; kk < 2; ++kk)
#pragma unroll
      for (int mi = 0; mi < 4; ++mi)
#pragma unroll
        for (int ni = 0; ni < 2; ++ni)
          acc[mi][ni + 2] = __builtin_amdgcn_mfma_f32_16x16x32_bf16(
              a0[mi][kk], b23[ni][kk], acc[mi][ni + 2], 0, 0, 0);
    __builtin_amdgcn_s_setprio(0);
    if (pr) {
      if (pf) { asm volatile("s_waitcnt vmcnt(8)" ::: "memory"); }
      else    { asm volatile("s_waitcnt vmcnt(0)" ::: "memory"); }
      FENCE();
    }
    BAR2();
  }

  // Epilogue: C/D layout col=lane&15, row=(lane>>4)*4+reg (m89-verified).
  const int colq = lane & 15;
  const int rq4  = (lane >> 4) * 4;
#pragma unroll
  for (int ni = 0; ni < 4; ++ni) {
    const int col = rowB0 + wn * 64 + ni * 16 + colq;
    const float bias = bmu[col] + beps[col] * __expf(0.5f * blv[col]);
#pragma unroll
    for (int mi = 0; mi < 8; ++mi) {
      const int rbase = rowA0 + wm * 128 + mi * 16 + rq4;
#pragma unroll
      for (int r = 0; r < 4; ++r)
        C[(size_t)(rbase + r) * N + col] = acc[mi][ni][r] + bias;
    }
  }
#undef GLL
#undef SA_LO
#undef SA_HI
#undef SB_LO
#undef SB_HI
#undef FENCE
#undef BAR1
#undef DRAIN
#undef BAR2
}

extern "C" void kernel_launch(void* const* d_in, const int* in_sizes, int n_in,
                              void* d_out, int out_size, void* d_ws, size_t ws_size,
                              hipStream_t stream) {
  const float* x    = (const float*)d_in[0];
  const float* wmu  = (const float*)d_in[1];
  const float* wlv  = (const float*)d_in[2];
  const float* bmu  = (const float*)d_in[3];
  const float* blv  = (const float*)d_in[4];
  const float* weps = (const float*)d_in[5];
  const float* beps = (const float*)d_in[6];
  float* out = (float*)d_out;

  const int M = 8192, N = 4096, K = 4096;

  // workspace: xbf [M*K] bf16 (64 MB) then wbf [N*K] bf16 (32 MB)
  unsigned short* xbf = (unsigned short*)d_ws;
  unsigned short* wbf = xbf + (size_t)M * K;

  const int n8w = N * K / 8;
  prep_weight<<<n8w / 256, 256, 0, stream>>>(
      (const float4*)wmu, (const float4*)wlv, (const float4*)weps,
      (u16x8*)wbf, n8w);
  const int n8x = M * K / 8;
  prep_x<<<n8x / 256, 256, 0, stream>>>((const float4*)x, (u16x8*)xbf, n8x);

  dim3 grid(N / 256, M / 256);  // 16 x 32 = 512 blocks
  gemm_bt_bias<<<grid, 512, 0, stream>>>(xbf, wbf, bmu, blv, beps, out, M, N, K);
}